// Round 5
// baseline (734.760 us; speedup 1.0000x reference)
//
#include <hip/hip_runtime.h>
#include <math.h>

typedef __bf16 bf16_t;
typedef bf16_t bf16x8 __attribute__((ext_vector_type(8)));
typedef bf16_t bf16x4 __attribute__((ext_vector_type(4)));
typedef float f32x4 __attribute__((ext_vector_type(4)));
typedef float f32x16 __attribute__((ext_vector_type(16)));

#define BB 4
#define SS 2048
#define HD1 1024
#define NH 16
#define DFF_ 4096

__device__ __forceinline__ void gload_lds16(const bf16_t* g, bf16_t* l) {
  __builtin_amdgcn_global_load_lds(
      (const __attribute__((address_space(1))) void*)g,
      (__attribute__((address_space(3))) void*)l, 16, 0, 0);
}

__device__ __forceinline__ unsigned pack2_bf16(float a, float b) {
  union { bf16_t h[2]; unsigned u; } cv;
  cv.h[0] = (bf16_t)a;
  cv.h[1] = (bf16_t)b;
  return cv.u;
}

// ---------------- LayerNorm: fp32 in -> bf16 out, one block per row ---------
__device__ __forceinline__ float block_reduce_sum(float v, float* red) {
  const int lane = threadIdx.x & 63;
  const int wid = threadIdx.x >> 6;
#pragma unroll
  for (int off = 32; off > 0; off >>= 1) v += __shfl_down(v, off, 64);
  if (lane == 0) red[wid] = v;
  __syncthreads();
  float s = red[0] + red[1] + red[2] + red[3];
  __syncthreads();
  return s;
}

__global__ __launch_bounds__(256) void ln_kernel(const float* __restrict__ x,
                                                 const float* __restrict__ w,
                                                 const float* __restrict__ bv,
                                                 bf16_t* __restrict__ out) {
  __shared__ float red[4];
  const size_t row = blockIdx.x;
  const float4 xv = *(const float4*)(x + row * HD1 + threadIdx.x * 4);
  float s = xv.x + xv.y + xv.z + xv.w;
  s = block_reduce_sum(s, red);
  const float mu = s * (1.0f / HD1);
  float4 d;
  d.x = xv.x - mu; d.y = xv.y - mu; d.z = xv.z - mu; d.w = xv.w - mu;
  float sq = d.x * d.x + d.y * d.y + d.z * d.z + d.w * d.w;
  sq = block_reduce_sum(sq, red);
  const float rs = rsqrtf(sq * (1.0f / HD1) + 1e-12f);
  const float4 wv = *(const float4*)(w + threadIdx.x * 4);
  const float4 bb = *(const float4*)(bv + threadIdx.x * 4);
  bf16x4 o;
  o[0] = (bf16_t)(d.x * rs * wv.x + bb.x);
  o[1] = (bf16_t)(d.y * rs * wv.y + bb.y);
  o[2] = (bf16_t)(d.z * rs * wv.z + bb.z);
  o[3] = (bf16_t)(d.w * rs * wv.w + bb.w);
  *(bf16x4*)(out + row * HD1 + threadIdx.x * 4) = o;
}

// ---------------- Weight convert+transpose: W[K][N] f32 -> Wt[N][K] bf16 ----
__global__ __launch_bounds__(256) void wt_kernel(const float* __restrict__ W,
                                                 bf16_t* __restrict__ Wt,
                                                 int K, int N) {
  __shared__ bf16_t T[32][33];
  const int t = threadIdx.x;
  const int n0 = blockIdx.x * 32, k0 = blockIdx.y * 32;
  const int a = t >> 5, c = t & 31;
#pragma unroll
  for (int i = 0; i < 4; ++i) {
    const int kl = a + i * 8;
    T[kl][c] = (bf16_t)W[(size_t)(k0 + kl) * N + n0 + c];
  }
  __syncthreads();
#pragma unroll
  for (int i = 0; i < 4; ++i) {
    const int nl = a + i * 8;
    Wt[(size_t)(n0 + nl) * K + k0 + c] = T[c][nl];
  }
}

// ---------------- V transpose: qkv[b][s][2H + h*64 + d] -> Vt[b][h][d][s] ---
__global__ __launch_bounds__(256) void vtrans_kernel(const bf16_t* __restrict__ qkv,
                                                     bf16_t* __restrict__ Vt) {
  const int t = threadIdx.x;
  const int s = blockIdx.x * 256 + t;
  const int head = blockIdx.y, b = blockIdx.z;
  const bf16_t* src = qkv + (size_t)(b * SS + s) * 3072 + 2048 + head * 64;
  bf16_t* dst = Vt + ((size_t)(b * NH + head) * 64) * SS + s;
#pragma unroll
  for (int j = 0; j < 8; ++j) {
    bf16x8 v = *(const bf16x8*)(src + j * 8);
#pragma unroll
    for (int e = 0; e < 8; ++e) dst[(size_t)(j * 8 + e) * SS] = v[e];
  }
}

// ---------------- MFMA GEMM: 256-class tiles, BK=64, 2-phase dbuf -----------
// C[M][N] = A[M][K] @ Wt[N][K]^T + epilogue
// 512 threads = 8 waves in WM x WN grid; per-wave tile (BM/WM)x(BN/WN).
// EPI: 0=bias, 1=bias+exact GELU, 2=bias+residual(f32).  OBF: bf16 output.
template <int BM, int BN, int WM, int WN, int EPI, bool OBF>
__global__ __launch_bounds__(512) void gemm_bf16(
    const bf16_t* __restrict__ A, const bf16_t* __restrict__ Wt,
    const float* __restrict__ bias, const float* __restrict__ R,
    void* __restrict__ Cout, int M, int N, int K) {
  constexpr int AST = BM * 64;  // elems per A K-tile
  constexpr int BST = BN * 64;
  constexpr size_t STAGE_B = (size_t)2 * (AST + BST) * 2;
  constexpr size_t EPI_B = OBF ? (size_t)128 * BN * 4 : 0;
  constexpr size_t SMEM_B = STAGE_B > EPI_B ? STAGE_B : EPI_B;
  __shared__ __align__(16) char smem[SMEM_B];
  bf16_t* As0 = (bf16_t*)smem;
  bf16_t* Bs0 = (bf16_t*)smem + 2 * AST;

  const int tid = threadIdx.x;
  const int lane = tid & 63;
  const int w = tid >> 6;
  const int l15 = lane & 15, l4 = lane >> 4;
  constexpr int WROWS = BM / WM;
  constexpr int WCOLS = BN / WN;
  constexpr int MF = WROWS / 16;
  constexpr int NF = WCOLS / 16;
  const int wr = w / WN, wc = w % WN;
  const int wrow0 = wr * WROWS, wcol0 = wc * WCOLS;

  // bijective XCD swizzle (all grids have nwg % 8 == 0)
  const int gx = gridDim.x;
  int id = blockIdx.x + gx * blockIdx.y;
  const int cpx = (gx * gridDim.y) >> 3;
  id = (id & 7) * cpx + (id >> 3);
  const int m0 = (id / gx) * BM;
  const int n0 = (id % gx) * BN;

  // staging: lane covers row tid/8 (0..63) per chunk, 16B at col (tid&7)*8
  const int srow = tid >> 3;
  const int scol8 = (tid & 7) * 8;
  const bf16_t* Ag0 = A + (size_t)(m0 + srow) * K + scol8;
  const bf16_t* Bg0 = Wt + (size_t)(n0 + srow) * K + scol8;

#define STAGE_TILE(T, BUF)                                              \
  do {                                                                  \
    const bf16_t* Ag = Ag0 + (size_t)(T)*64;                            \
    const bf16_t* Bg = Bg0 + (size_t)(T)*64;                            \
    bf16_t* Ad = As0 + (BUF)*AST + w * 512;                             \
    bf16_t* Bd = Bs0 + (BUF)*BST + w * 512;                             \
    _Pragma("unroll") for (int c = 0; c < BM / 64; ++c)                 \
        gload_lds16(Ag + (size_t)c * 64 * K, Ad + c * 4096);            \
    _Pragma("unroll") for (int c = 0; c < BN / 64; ++c)                 \
        gload_lds16(Bg + (size_t)c * 64 * K, Bd + c * 4096);            \
  } while (0)

  STAGE_TILE(0, 0);

  const int NT = K >> 6;
  f32x4 acc[MF][NF] = {};

  for (int t = 0; t < NT; ++t) {
    const int cur = t & 1;
    __syncthreads();  // drains buf[cur] stage; readers of buf[cur^1] done
    if (t + 1 < NT) STAGE_TILE(t + 1, cur ^ 1);
    const bf16_t* Ab = As0 + cur * AST;
    const bf16_t* Bb = Bs0 + cur * BST;
#pragma unroll
    for (int kk = 0; kk < 2; ++kk) {
      bf16x8 af[MF], bfr[NF];
#pragma unroll
      for (int i = 0; i < MF; ++i)
        af[i] = *(const bf16x8*)(Ab + (wrow0 + i * 16 + l15) * 64 + kk * 32 +
                                 l4 * 8);
#pragma unroll
      for (int j = 0; j < NF; ++j)
        bfr[j] = *(const bf16x8*)(Bb + (wcol0 + j * 16 + l15) * 64 + kk * 32 +
                                  l4 * 8);
#pragma unroll
      for (int i = 0; i < MF; ++i)
#pragma unroll
        for (int j = 0; j < NF; ++j)
          acc[i][j] = __builtin_amdgcn_mfma_f32_16x16x32_bf16(af[i], bfr[j],
                                                              acc[i][j], 0, 0, 0);
    }
  }
#undef STAGE_TILE

  if (OBF) {
    // bf16 output: LDS round-trip in 128-row passes, XOR quad-swizzled
    float* Cs = (float*)smem;
    bf16_t* Cb = (bf16_t*)Cout;
    constexpr int NP = BM / 128;
#pragma unroll
    for (int p = 0; p < NP; ++p) {
      __syncthreads();
#pragma unroll
      for (int i = 0; i < MF; ++i) {
        const int fr0 = wrow0 + i * 16;  // wave-uniform
        if ((fr0 >> 7) == p) {
#pragma unroll
          for (int j = 0; j < NF; ++j) {
            const int col = wcol0 + j * 16 + l15;
            const float bj = bias[n0 + col];
#pragma unroll
            for (int r = 0; r < 4; ++r) {
              float v = acc[i][j][r] + bj;
              if (EPI == 1)
                v = 0.5f * v * (1.0f + erff(v * 0.70710678118654752440f));
              const int lr = (fr0 & 127) + l4 * 4 + r;
              const int q = ((col >> 2) ^ (lr & 7)) << 2;
              Cs[lr * BN + q + (col & 3)] = v;
            }
          }
        }
      }
      __syncthreads();
      const int orow = tid >> 2;
      const int oc = tid & 3;
#pragma unroll
      for (int k = 0; k < BN / 32; ++k) {
        const int col = k * 32 + oc * 8;
        const int q0 = ((col >> 2) ^ (orow & 7)) << 2;
        const int q1 = (((col + 4) >> 2) ^ (orow & 7)) << 2;
        const f32x4 v0 = *(const f32x4*)(Cs + orow * BN + q0);
        const f32x4 v1 = *(const f32x4*)(Cs + orow * BN + q1);
        bf16x8 o;
        o[0] = (bf16_t)v0[0]; o[1] = (bf16_t)v0[1];
        o[2] = (bf16_t)v0[2]; o[3] = (bf16_t)v0[3];
        o[4] = (bf16_t)v1[0]; o[5] = (bf16_t)v1[1];
        o[6] = (bf16_t)v1[2]; o[7] = (bf16_t)v1[3];
        *(bf16x8*)(Cb + (size_t)(m0 + p * 128 + orow) * N + n0 + col) = o;
      }
    }
  } else {
    float* Cf = (float*)Cout;
#pragma unroll
    for (int j = 0; j < NF; ++j) {
      const int gn = n0 + wcol0 + j * 16 + l15;
      const float bj = bias[gn];
#pragma unroll
      for (int i = 0; i < MF; ++i) {
        const int gm = m0 + wrow0 + i * 16 + l4 * 4;
#pragma unroll
        for (int r = 0; r < 4; ++r) {
          float v = acc[i][j][r] + bj;
          if (EPI == 2) v += R[(size_t)(gm + r) * N + gn];
          Cf[(size_t)(gm + r) * N + gn] = v;
        }
      }
    }
  }
}

// ---------------- MFMA flash attention, swapped 32x32x16 structure ----------
__global__ __launch_bounds__(256, 2) void attn_kernel(
    const bf16_t* __restrict__ qkv, const bf16_t* __restrict__ Vt,
    const float* __restrict__ mask, bf16_t* __restrict__ ctx) {
  __shared__ __align__(16) bf16_t K_lds[64 * 72];   // [kv][d]
  __shared__ __align__(16) bf16_t Vt_lds[64 * 72];  // [dv][kv]
  const int tid = threadIdx.x;
  const int lane = tid & 63;
  const int w = tid >> 6;
  const int l31 = lane & 31;
  const int h = lane >> 5;
  const int q0 = blockIdx.x * 128;
  const int head = blockIdx.y;
  const int b = blockIdx.z;
  const int qrow = q0 + w * 32 + l31;

  bf16x8 qf[4];
  {
    const bf16_t* qp = qkv + (size_t)(b * SS + qrow) * 3072 + head * 64 + 8 * h;
#pragma unroll
    for (int ks = 0; ks < 4; ++ks) qf[ks] = *(const bf16x8*)(qp + 16 * ks);
  }

  const int srow = tid >> 2;
  const int scol = (tid & 3) * 16;

  float m = -3.0e38f, l = 0.0f;
  f32x16 cacc0 = {};
  f32x16 cacc1 = {};

  for (int kv0 = 0; kv0 < SS; kv0 += 64) {
    const bf16_t* kp =
        qkv + (size_t)(b * SS + kv0 + srow) * 3072 + 1024 + head * 64 + scol;
    const bf16_t* vp =
        Vt + ((size_t)(b * NH + head) * 64 + srow) * SS + kv0 + scol;
    const bf16x8 k0 = *(const bf16x8*)kp;
    const bf16x8 k1 = *(const bf16x8*)(kp + 8);
    const bf16x8 v0 = *(const bf16x8*)vp;
    const bf16x8 v1 = *(const bf16x8*)(vp + 8);
    float4 mv[8];
#pragma unroll
    for (int k2 = 0; k2 < 8; ++k2)
      mv[k2] = *(const float4*)(mask + (size_t)b * SS + kv0 + 8 * k2 + 4 * h);
    __syncthreads();
    *(bf16x8*)(K_lds + srow * 72 + scol) = k0;
    *(bf16x8*)(K_lds + srow * 72 + scol + 8) = k1;
    *(bf16x8*)(Vt_lds + srow * 72 + scol) = v0;
    *(bf16x8*)(Vt_lds + srow * 72 + scol + 8) = v1;
    __syncthreads();

    f32x16 sacc0 = {};
    f32x16 sacc1 = {};
#pragma unroll
    for (int ks = 0; ks < 4; ++ks) {
      const bf16x8 kf0 = *(const bf16x8*)(K_lds + l31 * 72 + 16 * ks + 8 * h);
      const bf16x8 kf1 =
          *(const bf16x8*)(K_lds + (l31 + 32) * 72 + 16 * ks + 8 * h);
      sacc0 = __builtin_amdgcn_mfma_f32_32x32x16_bf16(kf0, qf[ks], sacc0, 0, 0, 0);
      sacc1 = __builtin_amdgcn_mfma_f32_32x32x16_bf16(kf1, qf[ks], sacc1, 0, 0, 0);
    }

    float ps[32];
    float tmax = -3.0e38f;
#pragma unroll
    for (int r = 0; r < 16; ++r) {
      const float s0 = sacc0[r] * 0.125f + mv[(r >> 2)][r & 3];
      const float s1 = sacc1[r] * 0.125f + mv[(r >> 2) + 4][r & 3];
      ps[r] = s0;
      ps[16 + r] = s1;
      tmax = fmaxf(tmax, fmaxf(s0, s1));
    }
    tmax = fmaxf(tmax, __shfl_xor(tmax, 32, 64));
    if (__any(tmax > m + 8.0f)) {
      const float mnew = fmaxf(m, tmax);
      const float sc = __expf(m - mnew);
      m = mnew;
      l *= sc;
#pragma unroll
      for (int r = 0; r < 16; ++r) {
        const float scr = __shfl(sc, (r & 3) + 8 * (r >> 2) + 4 * h, 64);
        cacc0[r] *= scr;
        cacc1[r] *= scr;
      }
    }
    float ls = 0.0f;
#pragma unroll
    for (int i = 0; i < 32; ++i) {
      ps[i] = __expf(ps[i] - m);
      ls += ps[i];
    }
    l += ls + __shfl_xor(ls, 32, 64);

    unsigned pw0[8], pw1[8];
#pragma unroll
    for (int k = 0; k < 8; ++k) {
      const int base = (k >> 2) * 16 + (k & 3) * 4;
      pw0[k] = pack2_bf16(ps[base + 0], ps[base + 1]);
      pw1[k] = pack2_bf16(ps[base + 2], ps[base + 3]);
    }
#pragma unroll
    for (int t = 0; t < 4; ++t) {
      const unsigned e0 = h ? pw0[2 * t] : pw0[2 * t + 1];
      const unsigned e1 = h ? pw1[2 * t] : pw1[2 * t + 1];
      const unsigned o0 = (unsigned)__shfl_xor((int)e0, 32, 64);
      const unsigned o1 = (unsigned)__shfl_xor((int)e1, 32, 64);
      const unsigned a0 = h ? pw0[2 * t + 1] : pw0[2 * t];
      const unsigned a1 = h ? pw1[2 * t + 1] : pw1[2 * t];
      union { unsigned u[4]; bf16x8 v; } pu;
      pu.u[0] = h ? o0 : a0;
      pu.u[1] = h ? o1 : a1;
      pu.u[2] = h ? a0 : o0;
      pu.u[3] = h ? a1 : o1;
      const bf16x8 vf0 = *(const bf16x8*)(Vt_lds + l31 * 72 + 16 * t + 8 * h);
      const bf16x8 vf1 =
          *(const bf16x8*)(Vt_lds + (l31 + 32) * 72 + 16 * t + 8 * h);
      cacc0 = __builtin_amdgcn_mfma_f32_32x32x16_bf16(pu.v, vf0, cacc0, 0, 0, 0);
      cacc1 = __builtin_amdgcn_mfma_f32_32x32x16_bf16(pu.v, vf1, cacc1, 0, 0, 0);
    }
  }

  const float linv = 1.0f / l;
#pragma unroll
  for (int r = 0; r < 16; ++r) {
    const int rq = (r & 3) + 8 * (r >> 2) + 4 * h;
    const float li = __shfl(linv, rq, 64);
    const int grow = q0 + w * 32 + rq;
    bf16_t* op = ctx + (size_t)(b * SS + grow) * 1024 + head * 64 + l31;
    op[0] = (bf16_t)(cacc0[r] * li);
    op[32] = (bf16_t)(cacc1[r] * li);
  }
}

extern "C" void kernel_launch(void* const* d_in, const int* in_sizes, int n_in,
                              void* d_out, int out_size, void* d_ws, size_t ws_size,
                              hipStream_t stream) {
  const float* input    = (const float*)d_in[0];
  const float* mask     = (const float*)d_in[1];
  const float* norm_w   = (const float*)d_in[2];
  const float* norm_b   = (const float*)d_in[3];
  const float* qkv_w    = (const float*)d_in[4];
  const float* qkv_b    = (const float*)d_in[5];
  const float* attn_ow  = (const float*)d_in[6];
  const float* attn_ob  = (const float*)d_in[7];
  const float* attn_nw  = (const float*)d_in[8];
  const float* attn_nb  = (const float*)d_in[9];
  const float* inter_w  = (const float*)d_in[10];
  const float* inter_b  = (const float*)d_in[11];
  const float* output_w = (const float*)d_in[12];
  const float* output_b = (const float*)d_in[13];

  char* ws = (char*)d_ws;
  const size_t off_xln = 0;
  const size_t off_qkv = 16777216;
  const size_t off_vt  = 67108864;
  const size_t off_ctx = 83886080;
  const size_t off_ao  = 100663296;
  const size_t off_wq  = 134217728;
  const size_t off_wo  = 140509184;
  const size_t off_wi  = 142606336;
  const size_t off_w2  = 150994944;
  const size_t NEED    = 159383552;
  if (ws_size < NEED) return;

  bf16_t* x_ln  = (bf16_t*)(ws + off_xln);
  bf16_t* qkvb  = (bf16_t*)(ws + off_qkv);
  bf16_t* VtB   = (bf16_t*)(ws + off_vt);
  bf16_t* ctxb  = (bf16_t*)(ws + off_ctx);
  bf16_t* y_ln  = (bf16_t*)(ws + off_ctx);
  float*  a_out = (float*)(ws + off_ao);
  bf16_t* wq_t  = (bf16_t*)(ws + off_wq);
  bf16_t* wo_t  = (bf16_t*)(ws + off_wo);
  bf16_t* wi_t  = (bf16_t*)(ws + off_wi);
  bf16_t* w2_t  = (bf16_t*)(ws + off_w2);
  bf16_t* act   = (bf16_t*)(ws + off_xln);

  const int M = BB * SS;  // 8192

  wt_kernel<<<dim3(3072 / 32, 1024 / 32), 256, 0, stream>>>(qkv_w, wq_t, 1024, 3072);
  wt_kernel<<<dim3(1024 / 32, 1024 / 32), 256, 0, stream>>>(attn_ow, wo_t, 1024, 1024);
  wt_kernel<<<dim3(4096 / 32, 1024 / 32), 256, 0, stream>>>(inter_w, wi_t, 1024, 4096);
  wt_kernel<<<dim3(1024 / 32, 4096 / 32), 256, 0, stream>>>(output_w, w2_t, 4096, 1024);

  ln_kernel<<<M, 256, 0, stream>>>(input, norm_w, norm_b, x_ln);
  // qkv: 256x128 tile, 768 blocks (3/CU balanced)
  gemm_bf16<256, 128, 4, 2, 0, true><<<dim3(3072 / 128, M / 256), 512, 0, stream>>>(
      x_ln, wq_t, qkv_b, nullptr, qkvb, M, 3072, 1024);
  vtrans_kernel<<<dim3(SS / 256, NH, BB), 256, 0, stream>>>(qkvb, VtB);
  attn_kernel<<<dim3(SS / 128, NH, BB), 256, 0, stream>>>(qkvb, VtB, mask, ctxb);
  // proj: 256x128 tile, 256 blocks (1/CU)
  gemm_bf16<256, 128, 4, 2, 2, false><<<dim3(1024 / 128, M / 256), 512, 0, stream>>>(
      ctxb, wo_t, attn_ob, input, a_out, M, 1024, 1024);
  ln_kernel<<<M, 256, 0, stream>>>(a_out, attn_nw, attn_nb, y_ln);
  // FFN1: 256x256 tile, 512 blocks (2/CU)
  gemm_bf16<256, 256, 2, 4, 1, true><<<dim3(4096 / 256, M / 256), 512, 0, stream>>>(
      y_ln, wi_t, inter_b, nullptr, act, M, 4096, 1024);
  // FFN2: 256x128 tile, 256 blocks (1/CU)
  gemm_bf16<256, 128, 4, 2, 2, false><<<dim3(1024 / 128, M / 256), 512, 0, stream>>>(
      act, w2_t, output_b, a_out, (float*)d_out, M, 1024, 4096);
}

// Round 6
// 547.381 us; speedup vs baseline: 1.3423x; 1.3423x over previous
//
#include <hip/hip_runtime.h>
#include <math.h>

typedef __bf16 bf16_t;
typedef bf16_t bf16x8 __attribute__((ext_vector_type(8)));
typedef bf16_t bf16x4 __attribute__((ext_vector_type(4)));
typedef float f32x4 __attribute__((ext_vector_type(4)));
typedef float f32x16 __attribute__((ext_vector_type(16)));

#define BB 4
#define SS 2048
#define HD1 1024
#define NH 16
#define DFF_ 4096

__device__ __forceinline__ void gload_lds16(const bf16_t* g, bf16_t* l) {
  __builtin_amdgcn_global_load_lds(
      (const __attribute__((address_space(1))) void*)g,
      (__attribute__((address_space(3))) void*)l, 16, 0, 0);
}

__device__ __forceinline__ unsigned pack2_bf16(float a, float b) {
  union { bf16_t h[2]; unsigned u; } cv;
  cv.h[0] = (bf16_t)a;
  cv.h[1] = (bf16_t)b;
  return cv.u;
}

// ---------------- LayerNorm: fp32 in -> bf16 out, one block per row ---------
__device__ __forceinline__ float block_reduce_sum(float v, float* red) {
  const int lane = threadIdx.x & 63;
  const int wid = threadIdx.x >> 6;
#pragma unroll
  for (int off = 32; off > 0; off >>= 1) v += __shfl_down(v, off, 64);
  if (lane == 0) red[wid] = v;
  __syncthreads();
  float s = red[0] + red[1] + red[2] + red[3];
  __syncthreads();
  return s;
}

__global__ __launch_bounds__(256) void ln_kernel(const float* __restrict__ x,
                                                 const float* __restrict__ w,
                                                 const float* __restrict__ bv,
                                                 bf16_t* __restrict__ out) {
  __shared__ float red[4];
  const size_t row = blockIdx.x;
  const float4 xv = *(const float4*)(x + row * HD1 + threadIdx.x * 4);
  float s = xv.x + xv.y + xv.z + xv.w;
  s = block_reduce_sum(s, red);
  const float mu = s * (1.0f / HD1);
  float4 d;
  d.x = xv.x - mu; d.y = xv.y - mu; d.z = xv.z - mu; d.w = xv.w - mu;
  float sq = d.x * d.x + d.y * d.y + d.z * d.z + d.w * d.w;
  sq = block_reduce_sum(sq, red);
  const float rs = rsqrtf(sq * (1.0f / HD1) + 1e-12f);
  const float4 wv = *(const float4*)(w + threadIdx.x * 4);
  const float4 bb = *(const float4*)(bv + threadIdx.x * 4);
  bf16x4 o;
  o[0] = (bf16_t)(d.x * rs * wv.x + bb.x);
  o[1] = (bf16_t)(d.y * rs * wv.y + bb.y);
  o[2] = (bf16_t)(d.z * rs * wv.z + bb.z);
  o[3] = (bf16_t)(d.w * rs * wv.w + bb.w);
  *(bf16x4*)(out + row * HD1 + threadIdx.x * 4) = o;
}

// ---------------- Weight convert+transpose: W[K][N] f32 -> Wt[N][K] bf16 ----
__global__ __launch_bounds__(256) void wt_kernel(const float* __restrict__ W,
                                                 bf16_t* __restrict__ Wt,
                                                 int K, int N) {
  __shared__ bf16_t T[32][33];
  const int t = threadIdx.x;
  const int n0 = blockIdx.x * 32, k0 = blockIdx.y * 32;
  const int a = t >> 5, c = t & 31;
#pragma unroll
  for (int i = 0; i < 4; ++i) {
    const int kl = a + i * 8;
    T[kl][c] = (bf16_t)W[(size_t)(k0 + kl) * N + n0 + c];
  }
  __syncthreads();
#pragma unroll
  for (int i = 0; i < 4; ++i) {
    const int nl = a + i * 8;
    Wt[(size_t)(n0 + nl) * K + k0 + c] = T[c][nl];
  }
}

// ---------------- V transpose: qkv[b][s][2H + h*64 + d] -> Vt[b][h][d][s] ---
__global__ __launch_bounds__(256) void vtrans_kernel(const bf16_t* __restrict__ qkv,
                                                     bf16_t* __restrict__ Vt) {
  const int t = threadIdx.x;
  const int s = blockIdx.x * 256 + t;
  const int head = blockIdx.y, b = blockIdx.z;
  const bf16_t* src = qkv + (size_t)(b * SS + s) * 3072 + 2048 + head * 64;
  bf16_t* dst = Vt + ((size_t)(b * NH + head) * 64) * SS + s;
#pragma unroll
  for (int j = 0; j < 8; ++j) {
    bf16x8 v = *(const bf16x8*)(src + j * 8);
#pragma unroll
    for (int e = 0; e < 8; ++e) dst[(size_t)(j * 8 + e) * SS] = v[e];
  }
}

// ================= 8-phase counted-vmcnt GEMM (T2+T3+T4+T5) =================
// BM=128, BN=256, BK=64, 512 thr (8 waves: 2M x 4N), per-wave 64x64 out.
// LDS: A halves 2dbuf x 2half x 64x64, B halves 2dbuf x 2half x 128x64 = 96KB.
// Swizzle: LDS slot (row, chunk) holds global chunk (chunk ^ (row&7)); staged
// via pre-swizzled global source (linear gload_lds dest), read with same XOR.
// EPI: 0=bias, 1=bias+exact GELU, 2=bias+residual(f32).  OBF: bf16 output.
#define BAR() __builtin_amdgcn_s_barrier()
#define LGKM0()                                         \
  do {                                                  \
    asm volatile("s_waitcnt lgkmcnt(0)" ::: "memory");  \
    __builtin_amdgcn_sched_barrier(0);                  \
  } while (0)
#define VM4 asm volatile("s_waitcnt vmcnt(4)" ::: "memory")
#define VM0 asm volatile("s_waitcnt vmcnt(0)" ::: "memory")
#define PRIO1 __builtin_amdgcn_s_setprio(1)
#define PRIO0 __builtin_amdgcn_s_setprio(0)

template <int EPI, bool OBF>
__global__ __launch_bounds__(512) void gemm8p(
    const bf16_t* __restrict__ A, const bf16_t* __restrict__ Wt,
    const float* __restrict__ bias, const float* __restrict__ R,
    void* __restrict__ Cout, int M, int N, int K) {
  __shared__ __align__(16) char smem[98304];
  bf16_t* As = (bf16_t*)smem;                // [2][2][64*64]
  bf16_t* Bs = (bf16_t*)(smem + 32768);      // [2][2][2][64*64] (dbuf,half,k)

  const int tid = threadIdx.x;
  const int lane = tid & 63;
  const int w = tid >> 6;
  const int l15 = lane & 15, l4 = lane >> 4;
  const int wr = w >> 2;        // 0..1  A-half / row group
  const int wc = w & 3;         // 0..3  col group
  const int bh = wc >> 1;       // B-half
  const int bro = (wc & 1) * 64;

  // bijective XCD swizzle (all grids have nwg % 8 == 0)
  const int gx = gridDim.x;
  int id = blockIdx.x + gx * blockIdx.y;
  const int cpx = (gx * gridDim.y) >> 3;
  id = (id & 7) * cpx + (id >> 3);
  const int m0 = (id / gx) * 128;
  const int n0 = (id % gx) * 256;

  // staging: lane covers row tid>>3 of the half, 16B chunk pre-swizzled
  const int srow = tid >> 3;
  const int scol = (((tid & 7) ^ ((tid >> 3) & 7)) * 8);
  const bf16_t* Ag = A + (size_t)(m0 + srow) * K + scol;
  const bf16_t* Bg = Wt + (size_t)(n0 + srow) * K + scol;
  const size_t K64 = (size_t)64 * K;

  // swizzled read chunk offsets (elems) for ks=0,1
  const int chA0 = ((l4) ^ (l15 & 7)) * 8;
  const int chA1 = ((4 + l4) ^ (l15 & 7)) * 8;

#define STA(d, h, t)                                                       \
  gload_lds16(Ag + (size_t)(h)*64 * K + (size_t)(t)*64,                    \
              As + (d)*8192 + (h)*4096 + w * 512)
#define STB(d, h, t)                                                       \
  do {                                                                     \
    gload_lds16(Bg + (size_t)(h)*128 * K + (size_t)(t)*64,                 \
                Bs + (d)*16384 + (h)*8192 + w * 512);                      \
    gload_lds16(Bg + (size_t)(h)*128 * K + K64 + (size_t)(t)*64,           \
                Bs + (d)*16384 + (h)*8192 + 4096 + w * 512);               \
  } while (0)

  bf16x8 af[4][2], bfr[4][2];
  f32x4 acc[4][4] = {};

#define LDA(cur)                                                           \
  do {                                                                     \
    const bf16_t* Ah_ = As + (cur)*8192 + wr * 4096;                       \
    _Pragma("unroll") for (int i_ = 0; i_ < 4; ++i_) {                     \
      af[i_][0] = *(const bf16x8*)(Ah_ + (i_ * 16 + l15) * 64 + chA0);     \
      af[i_][1] = *(const bf16x8*)(Ah_ + (i_ * 16 + l15) * 64 + chA1);     \
    }                                                                      \
  } while (0)
#define LDB(cur, j0)                                                       \
  do {                                                                     \
    const bf16_t* Bh_ = Bs + (cur)*16384 + bh * 8192;                      \
    _Pragma("unroll") for (int j_ = (j0); j_ < (j0) + 2; ++j_) {           \
      bfr[j_][0] = *(const bf16x8*)(Bh_ + (bro + j_ * 16 + l15) * 64 + chA0); \
      bfr[j_][1] = *(const bf16x8*)(Bh_ + (bro + j_ * 16 + l15) * 64 + chA1); \
    }                                                                      \
  } while (0)
#define MM(i0, j0)                                                         \
  do {                                                                     \
    _Pragma("unroll") for (int ks_ = 0; ks_ < 2; ++ks_)                    \
    _Pragma("unroll") for (int i_ = 0; i_ < 2; ++i_)                       \
    _Pragma("unroll") for (int j_ = 0; j_ < 2; ++j_)                       \
        acc[(i0) + i_][(j0) + j_] = __builtin_amdgcn_mfma_f32_16x16x32_bf16( \
            af[(i0) + i_][ks_], bfr[(j0) + j_][ks_],                       \
            acc[(i0) + i_][(j0) + j_], 0, 0, 0);                           \
  } while (0)

  // prologue: tile0 full (6 loads) + tile1 A0,A1,B0 (4 loads)
  STA(0, 0, 0); STA(0, 1, 0); STB(0, 0, 0); STB(0, 1, 0);
  STA(1, 0, 1); STA(1, 1, 1); STB(1, 0, 1);
  VM4;
  BAR();

  const int NT = K >> 6;
  const int nIter = NT >> 1;
  for (int it = 0; it < nIter; ++it) {
    const int u = 2 * it;
    const bool lastI = (it == nIter - 1);
    // ---- phase 0 (tile u, dbuf0): reads af(all) + bfr[0..1]
    LDA(0);
    LDB(0, 0);
    STB(1, 1, u + 1);
    BAR(); LGKM0(); PRIO1; MM(0, 0); PRIO0; BAR();
    // ---- phase 1: reads bfr[2..3]
    LDB(0, 2);
    if (!lastI) STA(0, 0, u + 2);
    BAR(); LGKM0(); PRIO1; MM(2, 0); PRIO0; BAR();
    // ---- phase 2
    if (!lastI) STA(0, 1, u + 2);
    BAR(); PRIO1; MM(0, 2); PRIO0; BAR();
    // ---- phase 3 (vmcnt: tile u+1 complete)
    if (!lastI) { STB(0, 0, u + 2); VM4; } else { VM0; }
    BAR(); PRIO1; MM(2, 2); PRIO0; BAR();
    // ---- phase 4 (tile u+1, dbuf1)
    LDA(1);
    LDB(1, 0);
    if (!lastI) STB(0, 1, u + 2);
    BAR(); LGKM0(); PRIO1; MM(0, 0); PRIO0; BAR();
    // ---- phase 5
    LDB(1, 2);
    if (!lastI) STA(1, 0, u + 3);
    BAR(); LGKM0(); PRIO1; MM(2, 0); PRIO0; BAR();
    // ---- phase 6
    if (!lastI) STA(1, 1, u + 3);
    BAR(); PRIO1; MM(0, 2); PRIO0; BAR();
    // ---- phase 7 (vmcnt: tile u+2 complete)
    if (!lastI) { STB(1, 0, u + 3); VM4; }
    BAR(); PRIO1; MM(2, 2); PRIO0; BAR();
  }
#undef STA
#undef STB
#undef LDA
#undef LDB
#undef MM

  if (OBF) {
    // bf16 output via LDS round-trip, 2 passes of 64 rows, quad-XOR swizzle
    float* Cs = (float*)smem;  // 64 x 256 f32 = 64KB
    bf16_t* Cb = (bf16_t*)Cout;
    __syncthreads();
#pragma unroll
    for (int p = 0; p < 2; ++p) {
      if (p) __syncthreads();
      if (wr == p) {
#pragma unroll
        for (int i = 0; i < 4; ++i) {
#pragma unroll
          for (int j = 0; j < 4; ++j) {
            const int col = wc * 64 + j * 16 + l15;
            const float bj = bias[n0 + col];
#pragma unroll
            for (int r = 0; r < 4; ++r) {
              float v = acc[i][j][r] + bj;
              if (EPI == 1)
                v = 0.5f * v * (1.0f + erff(v * 0.70710678118654752440f));
              const int lr = i * 16 + l4 * 4 + r;  // 0..63
              const int q = (((col >> 2) ^ (lr & 7)) << 2);
              Cs[lr * 256 + q + (col & 3)] = v;
            }
          }
        }
      }
      __syncthreads();
      const int orow = tid >> 3;  // 0..63
      const int oc = tid & 7;
#pragma unroll
      for (int k = 0; k < 4; ++k) {
        const int col = k * 64 + oc * 8;
        const int q0 = ((((col >> 2) + 0) ^ (orow & 7)) << 2);
        const int q1 = ((((col >> 2) + 1) ^ (orow & 7)) << 2);
        const f32x4 v0 = *(const f32x4*)(Cs + orow * 256 + q0);
        const f32x4 v1 = *(const f32x4*)(Cs + orow * 256 + q1);
        bf16x8 o;
        o[0] = (bf16_t)v0[0]; o[1] = (bf16_t)v0[1];
        o[2] = (bf16_t)v0[2]; o[3] = (bf16_t)v0[3];
        o[4] = (bf16_t)v1[0]; o[5] = (bf16_t)v1[1];
        o[6] = (bf16_t)v1[2]; o[7] = (bf16_t)v1[3];
        *(bf16x8*)(Cb + (size_t)(m0 + p * 64 + orow) * N + n0 + col) = o;
      }
    }
  } else {
    float* Cf = (float*)Cout;
#pragma unroll
    for (int j = 0; j < 4; ++j) {
      const int gn = n0 + wc * 64 + j * 16 + l15;
      const float bj = bias[gn];
#pragma unroll
      for (int i = 0; i < 4; ++i) {
        const int gm = m0 + wr * 64 + i * 16 + l4 * 4;
#pragma unroll
        for (int r = 0; r < 4; ++r) {
          float v = acc[i][j][r] + bj;
          if (EPI == 2) v += R[(size_t)(gm + r) * N + gn];
          Cf[(size_t)(gm + r) * N + gn] = v;
        }
      }
    }
  }
}

// ---------------- MFMA flash attention, swapped 32x32x16 structure ----------
__global__ __launch_bounds__(256, 2) void attn_kernel(
    const bf16_t* __restrict__ qkv, const bf16_t* __restrict__ Vt,
    const float* __restrict__ mask, bf16_t* __restrict__ ctx) {
  __shared__ __align__(16) bf16_t K_lds[64 * 72];   // [kv][d]
  __shared__ __align__(16) bf16_t Vt_lds[64 * 72];  // [dv][kv]
  const int tid = threadIdx.x;
  const int lane = tid & 63;
  const int w = tid >> 6;
  const int l31 = lane & 31;
  const int h = lane >> 5;
  const int q0 = blockIdx.x * 128;
  const int head = blockIdx.y;
  const int b = blockIdx.z;
  const int qrow = q0 + w * 32 + l31;

  bf16x8 qf[4];
  {
    const bf16_t* qp = qkv + (size_t)(b * SS + qrow) * 3072 + head * 64 + 8 * h;
#pragma unroll
    for (int ks = 0; ks < 4; ++ks) qf[ks] = *(const bf16x8*)(qp + 16 * ks);
  }

  const int srow = tid >> 2;
  const int scol = (tid & 3) * 16;

  float m = -3.0e38f, l = 0.0f;
  f32x16 cacc0 = {};
  f32x16 cacc1 = {};

  for (int kv0 = 0; kv0 < SS; kv0 += 64) {
    const bf16_t* kp =
        qkv + (size_t)(b * SS + kv0 + srow) * 3072 + 1024 + head * 64 + scol;
    const bf16_t* vp =
        Vt + ((size_t)(b * NH + head) * 64 + srow) * SS + kv0 + scol;
    const bf16x8 k0 = *(const bf16x8*)kp;
    const bf16x8 k1 = *(const bf16x8*)(kp + 8);
    const bf16x8 v0 = *(const bf16x8*)vp;
    const bf16x8 v1 = *(const bf16x8*)(vp + 8);
    float4 mv[8];
#pragma unroll
    for (int k2 = 0; k2 < 8; ++k2)
      mv[k2] = *(const float4*)(mask + (size_t)b * SS + kv0 + 8 * k2 + 4 * h);
    __syncthreads();
    *(bf16x8*)(K_lds + srow * 72 + scol) = k0;
    *(bf16x8*)(K_lds + srow * 72 + scol + 8) = k1;
    *(bf16x8*)(Vt_lds + srow * 72 + scol) = v0;
    *(bf16x8*)(Vt_lds + srow * 72 + scol + 8) = v1;
    __syncthreads();

    f32x16 sacc0 = {};
    f32x16 sacc1 = {};
#pragma unroll
    for (int ks = 0; ks < 4; ++ks) {
      const bf16x8 kf0 = *(const bf16x8*)(K_lds + l31 * 72 + 16 * ks + 8 * h);
      const bf16x8 kf1 =
          *(const bf16x8*)(K_lds + (l31 + 32) * 72 + 16 * ks + 8 * h);
      sacc0 = __builtin_amdgcn_mfma_f32_32x32x16_bf16(kf0, qf[ks], sacc0, 0, 0, 0);
      sacc1 = __builtin_amdgcn_mfma_f32_32x32x16_bf16(kf1, qf[ks], sacc1, 0, 0, 0);
    }

    float ps[32];
    float tmax = -3.0e38f;
#pragma unroll
    for (int r = 0; r < 16; ++r) {
      const float s0 = sacc0[r] * 0.125f + mv[(r >> 2)][r & 3];
      const float s1 = sacc1[r] * 0.125f + mv[(r >> 2) + 4][r & 3];
      ps[r] = s0;
      ps[16 + r] = s1;
      tmax = fmaxf(tmax, fmaxf(s0, s1));
    }
    tmax = fmaxf(tmax, __shfl_xor(tmax, 32, 64));
    if (__any(tmax > m + 8.0f)) {
      const float mnew = fmaxf(m, tmax);
      const float sc = __expf(m - mnew);
      m = mnew;
      l *= sc;
#pragma unroll
      for (int r = 0; r < 16; ++r) {
        const float scr = __shfl(sc, (r & 3) + 8 * (r >> 2) + 4 * h, 64);
        cacc0[r] *= scr;
        cacc1[r] *= scr;
      }
    }
    float ls = 0.0f;
#pragma unroll
    for (int i = 0; i < 32; ++i) {
      ps[i] = __expf(ps[i] - m);
      ls += ps[i];
    }
    l += ls + __shfl_xor(ls, 32, 64);

    unsigned pw0[8], pw1[8];
#pragma unroll
    for (int k = 0; k < 8; ++k) {
      const int base = (k >> 2) * 16 + (k & 3) * 4;
      pw0[k] = pack2_bf16(ps[base + 0], ps[base + 1]);
      pw1[k] = pack2_bf16(ps[base + 2], ps[base + 3]);
    }
#pragma unroll
    for (int t = 0; t < 4; ++t) {
      const unsigned e0 = h ? pw0[2 * t] : pw0[2 * t + 1];
      const unsigned e1 = h ? pw1[2 * t] : pw1[2 * t + 1];
      const unsigned o0 = (unsigned)__shfl_xor((int)e0, 32, 64);
      const unsigned o1 = (unsigned)__shfl_xor((int)e1, 32, 64);
      const unsigned a0 = h ? pw0[2 * t + 1] : pw0[2 * t];
      const unsigned a1 = h ? pw1[2 * t + 1] : pw1[2 * t];
      union { unsigned u[4]; bf16x8 v; } pu;
      pu.u[0] = h ? o0 : a0;
      pu.u[1] = h ? o1 : a1;
      pu.u[2] = h ? a0 : o0;
      pu.u[3] = h ? a1 : o1;
      const bf16x8 vf0 = *(const bf16x8*)(Vt_lds + l31 * 72 + 16 * t + 8 * h);
      const bf16x8 vf1 =
          *(const bf16x8*)(Vt_lds + (l31 + 32) * 72 + 16 * t + 8 * h);
      cacc0 = __builtin_amdgcn_mfma_f32_32x32x16_bf16(pu.v, vf0, cacc0, 0, 0, 0);
      cacc1 = __builtin_amdgcn_mfma_f32_32x32x16_bf16(pu.v, vf1, cacc1, 0, 0, 0);
    }
  }

  const float linv = 1.0f / l;
#pragma unroll
  for (int r = 0; r < 16; ++r) {
    const int rq = (r & 3) + 8 * (r >> 2) + 4 * h;
    const float li = __shfl(linv, rq, 64);
    const int grow = q0 + w * 32 + rq;
    bf16_t* op = ctx + (size_t)(b * SS + grow) * 1024 + head * 64 + l31;
    op[0] = (bf16_t)(cacc0[r] * li);
    op[32] = (bf16_t)(cacc1[r] * li);
  }
}

extern "C" void kernel_launch(void* const* d_in, const int* in_sizes, int n_in,
                              void* d_out, int out_size, void* d_ws, size_t ws_size,
                              hipStream_t stream) {
  const float* input    = (const float*)d_in[0];
  const float* mask     = (const float*)d_in[1];
  const float* norm_w   = (const float*)d_in[2];
  const float* norm_b   = (const float*)d_in[3];
  const float* qkv_w    = (const float*)d_in[4];
  const float* qkv_b    = (const float*)d_in[5];
  const float* attn_ow  = (const float*)d_in[6];
  const float* attn_ob  = (const float*)d_in[7];
  const float* attn_nw  = (const float*)d_in[8];
  const float* attn_nb  = (const float*)d_in[9];
  const float* inter_w  = (const float*)d_in[10];
  const float* inter_b  = (const float*)d_in[11];
  const float* output_w = (const float*)d_in[12];
  const float* output_b = (const float*)d_in[13];

  char* ws = (char*)d_ws;
  const size_t off_xln = 0;
  const size_t off_qkv = 16777216;
  const size_t off_vt  = 67108864;
  const size_t off_ctx = 83886080;
  const size_t off_ao  = 100663296;
  const size_t off_wq  = 134217728;
  const size_t off_wo  = 140509184;
  const size_t off_wi  = 142606336;
  const size_t off_w2  = 150994944;
  const size_t NEED    = 159383552;
  if (ws_size < NEED) return;

  bf16_t* x_ln  = (bf16_t*)(ws + off_xln);
  bf16_t* qkvb  = (bf16_t*)(ws + off_qkv);
  bf16_t* VtB   = (bf16_t*)(ws + off_vt);
  bf16_t* ctxb  = (bf16_t*)(ws + off_ctx);
  bf16_t* y_ln  = (bf16_t*)(ws + off_ctx);
  float*  a_out = (float*)(ws + off_ao);
  bf16_t* wq_t  = (bf16_t*)(ws + off_wq);
  bf16_t* wo_t  = (bf16_t*)(ws + off_wo);
  bf16_t* wi_t  = (bf16_t*)(ws + off_wi);
  bf16_t* w2_t  = (bf16_t*)(ws + off_w2);
  bf16_t* act   = (bf16_t*)(ws + off_xln);

  const int M = BB * SS;  // 8192

  wt_kernel<<<dim3(3072 / 32, 1024 / 32), 256, 0, stream>>>(qkv_w, wq_t, 1024, 3072);
  wt_kernel<<<dim3(1024 / 32, 1024 / 32), 256, 0, stream>>>(attn_ow, wo_t, 1024, 1024);
  wt_kernel<<<dim3(4096 / 32, 1024 / 32), 256, 0, stream>>>(inter_w, wi_t, 1024, 4096);
  wt_kernel<<<dim3(1024 / 32, 4096 / 32), 256, 0, stream>>>(output_w, w2_t, 4096, 1024);

  ln_kernel<<<M, 256, 0, stream>>>(input, norm_w, norm_b, x_ln);
  // qkv: 768 blocks (3/CU)
  gemm8p<0, true><<<dim3(3072 / 256, M / 128), 512, 0, stream>>>(
      x_ln, wq_t, qkv_b, nullptr, qkvb, M, 3072, 1024);
  vtrans_kernel<<<dim3(SS / 256, NH, BB), 256, 0, stream>>>(qkvb, VtB);
  attn_kernel<<<dim3(SS / 128, NH, BB), 256, 0, stream>>>(qkvb, VtB, mask, ctxb);
  // proj: 256 blocks (1/CU)
  gemm8p<2, false><<<dim3(1024 / 256, M / 128), 512, 0, stream>>>(
      ctxb, wo_t, attn_ob, input, a_out, M, 1024, 1024);
  ln_kernel<<<M, 256, 0, stream>>>(a_out, attn_nw, attn_nb, y_ln);
  // FFN1: 1024 blocks (4/CU rounds)
  gemm8p<1, true><<<dim3(4096 / 256, M / 128), 512, 0, stream>>>(
      y_ln, wi_t, inter_b, nullptr, act, M, 4096, 1024);
  // FFN2: 256 blocks (1/CU), K=4096
  gemm8p<2, false><<<dim3(1024 / 256, M / 128), 512, 0, stream>>>(
      act, w2_t, output_b, a_out, (float*)d_out, M, 1024, 4096);
}